// Round 5
// baseline (77.732 us; speedup 1.0000x reference)
//
#include <hip/hip_runtime.h>
#include <math.h>
#include <stdint.h>

// KANLayer: out[b,o] = sum_i C[i,o]*(sum_k basis_k(x[b,i])*W[i,o,k] + bias[i,o])
// = GEMM: out = feats[4096 x 1152] * Weff[1152 x 128] + bterm[o]
// R5: best structure = R2 (two kernels; coop R3 +37us, fat single-kernel R4 +2us).
//     vs R2: 32 rows/block (halves BT L2 traffic 75->37 MB), K-chunked A-LDS,
//     fast tanh via exp+rcp instead of library tanhf.

#define DIN   128
#define DOUT  128
#define NB    9
#define KK    (DIN * NB)        // 1152
#define BATCH 4096
#define ROWS  32                // batch rows per block
#define BCOLS 64                // out cols per block
#define CHUNK_I 64              // input dims per K-chunk
#define CHUNK_K (CHUNK_I * NB)  // 576
#define NCHUNK  (DIN / CHUNK_I) // 2
#define ASTR  (CHUNK_K + 8)     // 584 bf16 row stride
#define NTHR  512

typedef __bf16 bf16x8 __attribute__((ext_vector_type(8)));
typedef float  f32x4  __attribute__((ext_vector_type(4)));

// ---------------- kernel 1: fold W*C -> BT (bf16, transposed) + bterm --------
__global__ __launch_bounds__(256) void fold_kernel(const float* __restrict__ W,
                                                   const float* __restrict__ bias,
                                                   const float* __restrict__ C,
                                                   __bf16* __restrict__ BT,
                                                   float* __restrict__ bterm) {
    const int idx = blockIdx.x * 256 + threadIdx.x;   // 0 .. 147455
    const int o = idx / KK;
    const int r = idx - o * KK;
    const int i = r / NB;
    const int k = r - i * NB;
    const float w = W[((size_t)i * DOUT + o) * NB + k];
    const float c = C[i * DOUT + o];
    BT[idx] = (__bf16)(w * c);

    if (blockIdx.x == 0 && threadIdx.x < DOUT) {
        const int oo = threadIdx.x;
        float s = 0.0f;
        #pragma unroll 8
        for (int ii = 0; ii < DIN; ++ii)
            s += bias[ii * DOUT + oo] * C[ii * DOUT + oo];
        bterm[oo] = s;
    }
}

// ---------------- kernel 2: fused basis expansion + MFMA GEMM ----------------
// 256 blocks (128 rowg x 2 colg) x 512 thr (8 waves = 2 row-tiles x 4 col-tiles).
// Per K-chunk (576): basis-expand 32x64 x-values into LDS A, then 18 MFMA
// K-steps per wave with B-frags straight from global BT (L2-resident).
// Layouts (HW-verified, guide §3): A-frag A[m][quad*8+j], B-frag BT[n][quad*8+j],
// C/D col=lane&15 row=quad*4+reg.
__global__ __launch_bounds__(NTHR, 1) void fused_kernel(const float* __restrict__ x,
                                                        const __bf16* __restrict__ BT,
                                                        const float* __restrict__ bterm,
                                                        float* __restrict__ out) {
    __shared__ __bf16 As[ROWS * ASTR];   // 37,376 B
    const int t    = threadIdx.x;
    const int rowg = blockIdx.x >> 1;
    const int colg = blockIdx.x & 1;
    const int row0 = rowg * ROWS;
    const int col0 = colg * BCOLS;

    const int lane = t & 63;
    const int wave = t >> 6;
    const int m    = lane & 15;
    const int quad = lane >> 4;
    const int rt   = wave >> 2;          // 0..1
    const int ct   = wave & 3;           // 0..3

    f32x4 acc = {0.0f, 0.0f, 0.0f, 0.0f};
    const __bf16* Bp = BT + (size_t)(col0 + ct * 16 + m) * KK + quad * 8;
    const __bf16* Ap = &As[(rt * 16 + m) * ASTR + quad * 8];

    for (int c = 0; c < NCHUNK; ++c) {
        if (c > 0) __syncthreads();      // prior chunk's LDS reads done

        // ---- basis expansion -> As[r][i_l*9+k]; 2048 values, 4 per thread ----
        #pragma unroll
        for (int pass = 0; pass < 4; ++pass) {
            const int e   = t + pass * NTHR;     // 0..2047
            const int r   = e >> 6;              // 0..31
            const int i_l = e & 63;
            const float v  = x[(size_t)(row0 + r) * DIN + c * CHUNK_I + i_l];
            const float av = fabsf(v);
            const float e2 = __expf(2.0f * v);
            float f[NB];
            f[0] = v;
            f[1] = v * v;
            f[2] = v * v * v;
            f[3] = __expf(v);
            f[4] = __logf(av + 1.0f);
            f[5] = __builtin_sqrtf(av);
            f[6] = 1.0f - 2.0f * __builtin_amdgcn_rcpf(e2 + 1.0f);  // tanh
            f[7] = __sinf(v);
            f[8] = av;
            __bf16* dst = &As[r * ASTR + i_l * NB];
            #pragma unroll
            for (int k = 0; k < NB; ++k) dst[k] = (__bf16)f[k];
        }
        __syncthreads();

        // ---- MFMA: 18 K-steps of 32 ----
        #pragma unroll 3
        for (int kc = 0; kc < CHUNK_K / 32; ++kc) {
            bf16x8 a = *(const bf16x8*)(Ap + kc * 32);
            bf16x8 b = *(const bf16x8*)(Bp + c * CHUNK_K + kc * 32);
            acc = __builtin_amdgcn_mfma_f32_16x16x32_bf16(a, b, acc, 0, 0, 0);
        }
    }

    // ---- epilogue ----
    const float bt = bterm[col0 + ct * 16 + m];
    float* op = out + (size_t)(row0 + rt * 16 + quad * 4) * DOUT + col0 + ct * 16 + m;
    #pragma unroll
    for (int r = 0; r < 4; ++r) op[(size_t)r * DOUT] = acc[r] + bt;
}

// ---------------- launcher ---------------------------------------------------
extern "C" void kernel_launch(void* const* d_in, const int* in_sizes, int n_in,
                              void* d_out, int out_size, void* d_ws, size_t ws_size,
                              hipStream_t stream) {
    const float* x    = (const float*)d_in[0];   // [4096,128]
    const float* W    = (const float*)d_in[1];   // [128,128,9]
    const float* bias = (const float*)d_in[2];   // [128,128]
    const float* C    = (const float*)d_in[3];   // [128,128]
    float* out = (float*)d_out;                  // [4096,128]

    char* ws = (char*)d_ws;
    __bf16* BT    = (__bf16*)ws;                              // 294,912 B
    float*  bterm = (float*)(ws + (size_t)DOUT * KK * 2);     // 512 B

    fold_kernel<<<(DOUT * KK) / 256, 256, 0, stream>>>(W, bias, C, BT, bterm);
    fused_kernel<<<(BATCH / ROWS) * (DOUT / BCOLS), NTHR, 0, stream>>>(x, BT, bterm, out);
}

// Round 6
// 76.098 us; speedup vs baseline: 1.0215x; 1.0215x over previous
//
#include <hip/hip_runtime.h>
#include <math.h>

// KANLayer: out[b,o] = sum_i C[i,o]*(sum_k basis_k(x[b,i])*W[i,o,k] + bias[i,o])
// = GEMM: out = feats[4096 x 1152] * Weff[1152 x 128] + bterm[o]
// R6: revert to R2 (best measured, 74.5us) + fast tanh. Structural A/B history:
//     R1 3-kernel 87.0 | R2 2-kernel 74.5 | R3 coop 112.0 | R4 1-kernel 76.4 |
//     R5 chunked 77.7. Timed window is dominated by harness ws re-poison
//     (268 MB fills @ ~41us each in profile); kernel work itself ~5us.

#define DIN   128
#define DOUT  128
#define NB    9
#define KK    (DIN * NB)    // 1152
#define BATCH 4096
#define ROWS  16            // batch rows per block
#define APAD  8             // +8 bf16 -> row stride 580 dwords (2-way LDS aliasing, free)
#define ASTR  (KK + APAD)   // 1160

typedef __bf16 bf16x8 __attribute__((ext_vector_type(8)));
typedef float  f32x4  __attribute__((ext_vector_type(4)));

// ---------------- kernel 1: fold W*C -> BT (bf16, transposed) + bterm --------
__global__ __launch_bounds__(256) void fold_kernel(const float* __restrict__ W,
                                                   const float* __restrict__ bias,
                                                   const float* __restrict__ C,
                                                   __bf16* __restrict__ BT,
                                                   float* __restrict__ bterm) {
    const int idx = blockIdx.x * 256 + threadIdx.x;   // 0 .. 147455
    const int o = idx / KK;
    const int r = idx - o * KK;
    const int i = r / NB;
    const int k = r - i * NB;
    const float w = W[((size_t)i * DOUT + o) * NB + k];
    const float c = C[i * DOUT + o];
    BT[idx] = (__bf16)(w * c);

    if (blockIdx.x == 0 && threadIdx.x < DOUT) {
        const int oo = threadIdx.x;
        float s = 0.0f;
        #pragma unroll 8
        for (int ii = 0; ii < DIN; ++ii)
            s += bias[ii * DOUT + oo] * C[ii * DOUT + oo];
        bterm[oo] = s;
    }
}

// ---------------- kernel 2: fused basis expansion + MFMA GEMM ----------------
// 256 blocks x 512 threads (8 waves). Block: 16 batch rows x all 128 cols.
// Stage 1: 2048 x-values -> 9 basis funcs each -> LDS A[16][1160] bf16.
// Stage 2: wave w computes the 16x16 tile at cols w*16; A-frags from LDS,
//          B-frags from global (BT = 294 KB, L2-resident across all blocks).
// Layouts (HW-verified, guide §3): A-frag A[m=lane&15][k=quad*8+j],
// B-frag BT[n=lane&15][k=quad*8+j], C/D col=lane&15 row=quad*4+reg.
__global__ __launch_bounds__(512, 1) void fused_kernel(const float* __restrict__ x,
                                                       const __bf16* __restrict__ BT,
                                                       const float* __restrict__ bterm,
                                                       float* __restrict__ out) {
    __shared__ __bf16 As[ROWS * ASTR];   // 37120 B
    const int t    = threadIdx.x;
    const int row0 = blockIdx.x * ROWS;

    // ---- stage 1: basis expansion into LDS ----
    for (int e = t; e < ROWS * DIN; e += 512) {
        const int r = e >> 7;            // row within tile
        const int i = e & 127;           // din index
        const float v  = x[(size_t)(row0 + r) * DIN + i];
        const float av = fabsf(v);
        const float e2 = __expf(2.0f * v);
        float f[NB];
        f[0] = v;
        f[1] = v * v;
        f[2] = v * v * v;
        f[3] = __expf(v);
        f[4] = __logf(av + 1.0f);
        f[5] = __builtin_sqrtf(av);
        f[6] = 1.0f - 2.0f * __builtin_amdgcn_rcpf(e2 + 1.0f);  // tanh, rel-err ~1e-5
        f[7] = __sinf(v);
        f[8] = av;
        __bf16* dst = &As[r * ASTR + i * NB];
        #pragma unroll
        for (int k = 0; k < NB; ++k) dst[k] = (__bf16)f[k];
    }
    __syncthreads();

    // ---- stage 2: MFMA ----
    const int lane = t & 63;
    const int wave = t >> 6;             // 0..7 -> col tile
    const int m    = lane & 15;
    const int quad = lane >> 4;
    const int col0 = wave << 4;

    const __bf16* Ap = &As[m * ASTR + quad * 8];
    const __bf16* Bp = BT + (size_t)(col0 + m) * KK + quad * 8;

    f32x4 acc = {0.0f, 0.0f, 0.0f, 0.0f};

    #pragma unroll 6
    for (int kc = 0; kc < KK / 32; ++kc) {   // 36 iters
        bf16x8 a = *(const bf16x8*)(Ap + kc * 32);
        bf16x8 b = *(const bf16x8*)(Bp + kc * 32);
        acc = __builtin_amdgcn_mfma_f32_16x16x32_bf16(a, b, acc, 0, 0, 0);
    }

    const float bt = bterm[col0 + m];
    float* op = out + (size_t)(row0 + quad * 4) * DOUT + col0 + m;
    #pragma unroll
    for (int r = 0; r < 4; ++r) op[(size_t)r * DOUT] = acc[r] + bt;
}

// ---------------- launcher ---------------------------------------------------
extern "C" void kernel_launch(void* const* d_in, const int* in_sizes, int n_in,
                              void* d_out, int out_size, void* d_ws, size_t ws_size,
                              hipStream_t stream) {
    const float* x    = (const float*)d_in[0];   // [4096,128]
    const float* W    = (const float*)d_in[1];   // [128,128,9]
    const float* bias = (const float*)d_in[2];   // [128,128]
    const float* C    = (const float*)d_in[3];   // [128,128]
    float* out = (float*)d_out;                  // [4096,128]

    char* ws = (char*)d_ws;
    __bf16* BT    = (__bf16*)ws;                              // 128*1152*2 = 294,912 B
    float*  bterm = (float*)(ws + (size_t)DOUT * KK * 2);     // 512 B

    fold_kernel<<<(DOUT * KK) / 256, 256, 0, stream>>>(W, bias, C, BT, bterm);
    fused_kernel<<<BATCH / ROWS, 512, 0, stream>>>(x, BT, bterm, out);
}